// Round 1
// baseline (4002.024 us; speedup 1.0000x reference)
//
#include <hip/hip_runtime.h>
#include <math.h>

// Problem constants
#define BB 4
#define TT 2048
#define CC 1024
#define HH 16
#define DD 64
#define F3 3072   // 3*C
#define NTOK (BB*TT)  // 8192

// ---------------------------------------------------------------------------
// fp32 GEMM: C[M,N] = A[M,K] @ W[K,N] + bias[N]
// 64x64 tile, BK=16, 256 threads, 4x4 microtile per thread.
// LDS rows padded to 68 floats (272 B = 17*16 B) so float4 LDS accesses stay
// 16B-aligned; resulting bank aliasing is <=2-way (free on gfx950, m136).
// ---------------------------------------------------------------------------
__global__ __launch_bounds__(256) void gemm_bias_kernel(
    const float* __restrict__ A, const float* __restrict__ W,
    const float* __restrict__ bias, float* __restrict__ Cmat,
    int M, int N, int K)
{
    __shared__ float As[16][68];  // [k][m]
    __shared__ float Ws[16][68];  // [k][n]

    const int tid = threadIdx.x;
    const int n0 = blockIdx.x * 64;
    const int m0 = blockIdx.y * 64;
    const int tx = tid & 15;      // 16 col-groups
    const int ty = tid >> 4;      // 16 row-groups

    const int arow = tid >> 2;          // 0..63
    const int acol = (tid & 3) << 2;    // 0,4,8,12
    const int wrow = tid >> 4;          // 0..15
    const int wcol = (tid & 15) << 2;   // 0..60

    const float* Aptr = A + (long)(m0 + arow) * K + acol;
    const float* Wptr = W + (long)wrow * N + n0 + wcol;

    float acc[4][4] = {};

    for (int k0 = 0; k0 < K; k0 += 16) {
        float4 av = *(const float4*)(Aptr + k0);
        float4 wv = *(const float4*)(Wptr + (long)k0 * N);
        As[acol + 0][arow] = av.x;
        As[acol + 1][arow] = av.y;
        As[acol + 2][arow] = av.z;
        As[acol + 3][arow] = av.w;
        *(float4*)(&Ws[wrow][wcol]) = wv;
        __syncthreads();
        #pragma unroll
        for (int kk = 0; kk < 16; ++kk) {
            float4 a4 = *(const float4*)(&As[kk][ty << 2]);
            float4 b4 = *(const float4*)(&Ws[kk][tx << 2]);
            float a[4] = {a4.x, a4.y, a4.z, a4.w};
            float b[4] = {b4.x, b4.y, b4.z, b4.w};
            #pragma unroll
            for (int i = 0; i < 4; ++i)
                #pragma unroll
                for (int j = 0; j < 4; ++j)
                    acc[i][j] += a[i] * b[j];
        }
        __syncthreads();
    }

    #pragma unroll
    for (int i = 0; i < 4; ++i) {
        float4 o;
        float* op = &o.x;
        #pragma unroll
        for (int j = 0; j < 4; ++j)
            op[j] = acc[i][j] + bias[n0 + (tx << 2) + j];
        *(float4*)(Cmat + (long)(m0 + (ty << 2) + i) * N + n0 + (tx << 2)) = o;
    }
}

// ---------------------------------------------------------------------------
// Flash-style non-causal attention, fp32.
// Grid: (T/64, B*H). Block: 256 threads. Each block: 64 queries of one head.
// qkv layout: [B*T, 3072] with q at cols [0,1024), k at [1024,2048), v at [2048,3072).
// Per head h: dims h*64 .. h*64+63 within each 1024 chunk.
// Output y: [B*T, 1024] (i.e. [B,T,H*D]) ready for the projection GEMM.
// ---------------------------------------------------------------------------
__global__ __launch_bounds__(256) void attn_kernel(
    const float* __restrict__ qkv, float* __restrict__ y)
{
    __shared__ float Qs[64][68];
    __shared__ float KVs[64][68];
    __shared__ float Ps[64][68];
    __shared__ float row_m[64], row_l[64], row_alpha[64];

    const int tid = threadIdx.x;
    const int q0 = blockIdx.x * 64;
    const int bh = blockIdx.y;
    const int b = bh >> 4;   // / H
    const int h = bh & 15;
    const int tx = tid & 15;
    const int ty = tid >> 4;
    const long head_off = (long)h * 64;

    // Load Q tile [64 q][64 d]
    #pragma unroll
    for (int i = 0; i < 4; ++i) {
        int lin = tid + i * 256;
        int r = lin >> 4;
        int d = (lin & 15) << 2;
        const float* src = qkv + (long)(b * TT + q0 + r) * F3 + head_off + d;
        *(float4*)(&Qs[r][d]) = *(const float4*)src;
    }
    if (tid < 64) { row_m[tid] = -1e30f; row_l[tid] = 0.f; }
    float acc[4][4] = {};
    __syncthreads();

    for (int k0 = 0; k0 < TT; k0 += 64) {
        // Load K tile [64 k][64 d]
        #pragma unroll
        for (int i = 0; i < 4; ++i) {
            int lin = tid + i * 256;
            int r = lin >> 4;
            int d = (lin & 15) << 2;
            const float* src = qkv + (long)(b * TT + k0 + r) * F3 + 1024 + head_off + d;
            *(float4*)(&KVs[r][d]) = *(const float4*)src;
        }
        __syncthreads();

        // S = (Q K^T) * 0.125 ; 4x4 microtile per thread
        float s[4][4] = {};
        #pragma unroll
        for (int d4 = 0; d4 < 64; d4 += 4) {
            float4 aa[4], bb[4];
            #pragma unroll
            for (int i = 0; i < 4; ++i) aa[i] = *(const float4*)(&Qs[(ty << 2) + i][d4]);
            #pragma unroll
            for (int j = 0; j < 4; ++j) bb[j] = *(const float4*)(&KVs[(tx << 2) + j][d4]);
            #pragma unroll
            for (int i = 0; i < 4; ++i) {
                #pragma unroll
                for (int j = 0; j < 4; ++j) {
                    s[i][j] += aa[i].x * bb[j].x + aa[i].y * bb[j].y
                             + aa[i].z * bb[j].z + aa[i].w * bb[j].w;
                }
            }
        }
        #pragma unroll
        for (int i = 0; i < 4; ++i)
            #pragma unroll
            for (int j = 0; j < 4; ++j)
                Ps[(ty << 2) + i][(tx << 2) + j] = s[i][j] * 0.125f;
        __syncthreads();

        // Overlap: issue V loads (overwrites KVs; K reads are done) while
        // 64 threads run the online-softmax row update on Ps.
        float4 vtmp[4];
        int vr[4], vd[4];
        #pragma unroll
        for (int i = 0; i < 4; ++i) {
            int lin = tid + i * 256;
            vr[i] = lin >> 4;
            vd[i] = (lin & 15) << 2;
            const float* src = qkv + (long)(b * TT + k0 + vr[i]) * F3 + 2048 + head_off + vd[i];
            vtmp[i] = *(const float4*)src;
        }
        if (tid < 64) {
            float mold = row_m[tid];
            float mt = mold;
            #pragma unroll 8
            for (int k = 0; k < 64; ++k) mt = fmaxf(mt, Ps[tid][k]);
            float alpha = __expf(mold - mt);
            float sum = 0.f;
            #pragma unroll 8
            for (int k = 0; k < 64; ++k) {
                float p = __expf(Ps[tid][k] - mt);
                Ps[tid][k] = p;
                sum += p;
            }
            row_m[tid] = mt;
            row_l[tid] = row_l[tid] * alpha + sum;
            row_alpha[tid] = alpha;
        }
        #pragma unroll
        for (int i = 0; i < 4; ++i)
            *(float4*)(&KVs[vr[i]][vd[i]]) = vtmp[i];
        __syncthreads();

        // O = O*alpha + P @ V
        #pragma unroll
        for (int i = 0; i < 4; ++i) {
            float al = row_alpha[(ty << 2) + i];
            #pragma unroll
            for (int j = 0; j < 4; ++j) acc[i][j] *= al;
        }
        #pragma unroll
        for (int k4 = 0; k4 < 64; k4 += 4) {
            float4 pp[4];
            #pragma unroll
            for (int i = 0; i < 4; ++i) pp[i] = *(const float4*)(&Ps[(ty << 2) + i][k4]);
            #pragma unroll
            for (int l = 0; l < 4; ++l) {
                float4 vv = *(const float4*)(&KVs[k4 + l][tx << 2]);
                float pl[4] = {pp[0].x, pp[1].x, pp[2].x, pp[3].x};
                float* ppf0 = &pp[0].x; float* ppf1 = &pp[1].x;
                float* ppf2 = &pp[2].x; float* ppf3 = &pp[3].x;
                float p0 = ppf0[l], p1 = ppf1[l], p2 = ppf2[l], p3 = ppf3[l];
                (void)pl;
                float vb[4] = {vv.x, vv.y, vv.z, vv.w};
                #pragma unroll
                for (int j = 0; j < 4; ++j) {
                    acc[0][j] += p0 * vb[j];
                    acc[1][j] += p1 * vb[j];
                    acc[2][j] += p2 * vb[j];
                    acc[3][j] += p3 * vb[j];
                }
            }
        }
        __syncthreads();
    }

    // Normalize and write y[B*T, 1024]
    #pragma unroll
    for (int i = 0; i < 4; ++i) {
        float inv_l = 1.f / row_l[(ty << 2) + i];
        float4 o;
        o.x = acc[i][0] * inv_l;
        o.y = acc[i][1] * inv_l;
        o.z = acc[i][2] * inv_l;
        o.w = acc[i][3] * inv_l;
        float* dst = y + (long)(b * TT + q0 + (ty << 2) + i) * CC + head_off + (tx << 2);
        *(float4*)dst = o;
    }
}

extern "C" void kernel_launch(void* const* d_in, const int* in_sizes, int n_in,
                              void* d_out, int out_size, void* d_ws, size_t ws_size,
                              hipStream_t stream) {
    const float* x      = (const float*)d_in[0];  // [B,T,C]
    const float* w_attn = (const float*)d_in[1];  // [C, 3C]
    const float* b_attn = (const float*)d_in[2];  // [3C]
    const float* w_proj = (const float*)d_in[3];  // [C, C]
    const float* b_proj = (const float*)d_in[4];  // [C]
    float* out = (float*)d_out;                   // [B,T,C]

    float* qkv = (float*)d_ws;                    // [8192, 3072]  96 MB
    float* yws = qkv + (size_t)NTOK * F3;         // [8192, 1024]  32 MB

    // 1) QKV = x @ w_attn + b_attn
    {
        dim3 grid(F3 / 64, NTOK / 64);
        gemm_bias_kernel<<<grid, 256, 0, stream>>>(x, w_attn, b_attn, qkv,
                                                   NTOK, F3, CC);
    }
    // 2) attention -> y
    {
        dim3 grid(TT / 64, BB * HH);
        attn_kernel<<<grid, 256, 0, stream>>>(qkv, yws);
    }
    // 3) out = y @ w_proj + b_proj
    {
        dim3 grid(CC / 64, NTOK / 64);
        gemm_bias_kernel<<<grid, 256, 0, stream>>>(yws, w_proj, b_proj, out,
                                                   NTOK, CC, CC);
    }
}

// Round 2
// 2138.581 us; speedup vs baseline: 1.8713x; 1.8713x over previous
//
#include <hip/hip_runtime.h>
#include <math.h>

// Problem constants
#define BB 4
#define TT 2048
#define CC 1024
#define HH 16
#define DD 64
#define F3 3072   // 3*C
#define NTOK (BB*TT)  // 8192

// ---------------------------------------------------------------------------
// fp32 GEMM: C[M,N] = A[M,K] @ W[K,N] + bias[N]
// 64x64 tile, BK=16, 256 threads, 4x4 microtile per thread. (unchanged R1)
// ---------------------------------------------------------------------------
__global__ __launch_bounds__(256) void gemm_bias_kernel(
    const float* __restrict__ A, const float* __restrict__ W,
    const float* __restrict__ bias, float* __restrict__ Cmat,
    int M, int N, int K)
{
    __shared__ float As[16][68];  // [k][m]
    __shared__ float Ws[16][68];  // [k][n]

    const int tid = threadIdx.x;
    const int n0 = blockIdx.x * 64;
    const int m0 = blockIdx.y * 64;
    const int tx = tid & 15;
    const int ty = tid >> 4;

    const int arow = tid >> 2;
    const int acol = (tid & 3) << 2;
    const int wrow = tid >> 4;
    const int wcol = (tid & 15) << 2;

    const float* Aptr = A + (long)(m0 + arow) * K + acol;
    const float* Wptr = W + (long)wrow * N + n0 + wcol;

    float acc[4][4] = {};

    for (int k0 = 0; k0 < K; k0 += 16) {
        float4 av = *(const float4*)(Aptr + k0);
        float4 wv = *(const float4*)(Wptr + (long)k0 * N);
        As[acol + 0][arow] = av.x;
        As[acol + 1][arow] = av.y;
        As[acol + 2][arow] = av.z;
        As[acol + 3][arow] = av.w;
        *(float4*)(&Ws[wrow][wcol]) = wv;
        __syncthreads();
        #pragma unroll
        for (int kk = 0; kk < 16; ++kk) {
            float4 a4 = *(const float4*)(&As[kk][ty << 2]);
            float4 b4 = *(const float4*)(&Ws[kk][tx << 2]);
            float a[4] = {a4.x, a4.y, a4.z, a4.w};
            float b[4] = {b4.x, b4.y, b4.z, b4.w};
            #pragma unroll
            for (int i = 0; i < 4; ++i)
                #pragma unroll
                for (int j = 0; j < 4; ++j)
                    acc[i][j] += a[i] * b[j];
        }
        __syncthreads();
    }

    #pragma unroll
    for (int i = 0; i < 4; ++i) {
        float4 o;
        float* op = &o.x;
        #pragma unroll
        for (int j = 0; j < 4; ++j)
            op[j] = acc[i][j] + bias[n0 + (tx << 2) + j];
        *(float4*)(Cmat + (long)(m0 + (ty << 2) + i) * N + n0 + (tx << 2)) = o;
    }
}

// ---------------------------------------------------------------------------
// Flash attention v2 (fp32), register-resident online softmax.
// Grid: (T/64, B*H), 256 threads, 4x4 microtile per thread.
// LDS layouts chosen for conflict-free inner loops:
//   QsT[d][q]  (Q transposed, scale folded in)
//   KVs: K as [d][k] (transposed), then overwritten with V as [k][d] row-major
//   PsT[k][q]  (P transposed)
// S-loop:  per d: lanes read QsT[d][4ty..+3] (bcast x16 / consec) and
//          KsT[d][4tx..+3] (consec 16B x16 lanes -> <=2-way, free).
// PV-loop: per k: PsT[k][4ty..+3], Vs[k][4tx..+3] — same pattern.
// Softmax: per-thread 4-row partials + __shfl_xor butterfly over the 16
// lanes sharing a row-group (lanes are contiguous: tid = ty*16+tx).
// m/l/alpha in registers — no serial section, no LDS row state.
// ---------------------------------------------------------------------------
__global__ __launch_bounds__(256) void attn_kernel(
    const float* __restrict__ qkv, float* __restrict__ y)
{
    __shared__ float QsT[64][68];
    __shared__ float KVs[64][68];
    __shared__ float PsT[64][68];

    const int tid = threadIdx.x;
    const int q0 = blockIdx.x * 64;
    const int bh = blockIdx.y;
    const int b = bh >> 4;
    const int h = bh & 15;
    const int tx = tid & 15;
    const int ty = tid >> 4;
    const long head_off = (long)h * 64;
    const long rowbase = (long)(b * TT) * F3;

    // Stage Q transposed, fold in 1/sqrt(D) = 0.125
    #pragma unroll
    for (int i = 0; i < 4; ++i) {
        int lin = tid + i * 256;
        int r = lin >> 4;
        int d = (lin & 15) << 2;
        const float4 v = *(const float4*)(qkv + rowbase + (long)(q0 + r) * F3 + head_off + d);
        QsT[d + 0][r] = v.x * 0.125f;
        QsT[d + 1][r] = v.y * 0.125f;
        QsT[d + 2][r] = v.z * 0.125f;
        QsT[d + 3][r] = v.w * 0.125f;
    }

    float acc[4][4] = {};
    float m_run[4], l_run[4];
    #pragma unroll
    for (int i = 0; i < 4; ++i) { m_run[i] = -1e30f; l_run[i] = 0.f; }
    __syncthreads();

    for (int k0 = 0; k0 < TT; k0 += 64) {
        // K tile -> registers
        float4 kreg[4];
        int kr[4], kd[4];
        #pragma unroll
        for (int i = 0; i < 4; ++i) {
            int lin = tid + i * 256;
            kr[i] = lin >> 4;
            kd[i] = (lin & 15) << 2;
            kreg[i] = *(const float4*)(qkv + rowbase + (long)(k0 + kr[i]) * F3 + 1024 + head_off + kd[i]);
        }
        // K transposed scatter into KVs[d][k]
        #pragma unroll
        for (int i = 0; i < 4; ++i) {
            KVs[kd[i] + 0][kr[i]] = kreg[i].x;
            KVs[kd[i] + 1][kr[i]] = kreg[i].y;
            KVs[kd[i] + 2][kr[i]] = kreg[i].z;
            KVs[kd[i] + 3][kr[i]] = kreg[i].w;
        }
        __syncthreads();   // K visible

        // Issue V loads early (consumed after next barrier)
        float4 vreg[4];
        int vr[4], vd[4];
        #pragma unroll
        for (int i = 0; i < 4; ++i) {
            int lin = tid + i * 256;
            vr[i] = lin >> 4;
            vd[i] = (lin & 15) << 2;
            vreg[i] = *(const float4*)(qkv + rowbase + (long)(k0 + vr[i]) * F3 + 2048 + head_off + vd[i]);
        }

        // S = Q K^T (outer-product over d)
        float s[4][4] = {};
        #pragma unroll 16
        for (int d = 0; d < 64; ++d) {
            float4 q4 = *(const float4*)(&QsT[d][ty << 2]);
            float4 k4 = *(const float4*)(&KVs[d][tx << 2]);
            float qa[4] = {q4.x, q4.y, q4.z, q4.w};
            float kb[4] = {k4.x, k4.y, k4.z, k4.w};
            #pragma unroll
            for (int i = 0; i < 4; ++i)
                #pragma unroll
                for (int j = 0; j < 4; ++j)
                    s[i][j] += qa[i] * kb[j];
        }

        // Register online softmax
        float mt[4], alpha[4], rsum[4];
        #pragma unroll
        for (int i = 0; i < 4; ++i)
            mt[i] = fmaxf(fmaxf(s[i][0], s[i][1]), fmaxf(s[i][2], s[i][3]));
        #pragma unroll
        for (int off = 1; off < 16; off <<= 1) {
            #pragma unroll
            for (int i = 0; i < 4; ++i)
                mt[i] = fmaxf(mt[i], __shfl_xor(mt[i], off));
        }
        #pragma unroll
        for (int i = 0; i < 4; ++i) {
            float mn = fmaxf(m_run[i], mt[i]);
            alpha[i] = __expf(m_run[i] - mn);
            m_run[i] = mn;
        }
        #pragma unroll
        for (int i = 0; i < 4; ++i) {
            float t = 0.f;
            #pragma unroll
            for (int j = 0; j < 4; ++j) {
                s[i][j] = __expf(s[i][j] - m_run[i]);
                t += s[i][j];
            }
            rsum[i] = t;
        }
        #pragma unroll
        for (int off = 1; off < 16; off <<= 1) {
            #pragma unroll
            for (int i = 0; i < 4; ++i)
                rsum[i] += __shfl_xor(rsum[i], off);
        }
        #pragma unroll
        for (int i = 0; i < 4; ++i) {
            l_run[i] = l_run[i] * alpha[i] + rsum[i];
            #pragma unroll
            for (int j = 0; j < 4; ++j) acc[i][j] *= alpha[i];
        }

        __syncthreads();   // all K reads done -> KVs reusable for V

        // V row-major into KVs[k][d]; P transposed into PsT[k][q]
        #pragma unroll
        for (int i = 0; i < 4; ++i)
            *(float4*)(&KVs[vr[i]][vd[i]]) = vreg[i];
        #pragma unroll
        for (int j = 0; j < 4; ++j) {
            float4 pv = {s[0][j], s[1][j], s[2][j], s[3][j]};
            *(float4*)(&PsT[(tx << 2) + j][ty << 2]) = pv;
        }
        __syncthreads();   // V, P visible

        // O += P V (outer-product over k)
        #pragma unroll 16
        for (int k = 0; k < 64; ++k) {
            float4 p4 = *(const float4*)(&PsT[k][ty << 2]);
            float4 v4 = *(const float4*)(&KVs[k][tx << 2]);
            float pa[4] = {p4.x, p4.y, p4.z, p4.w};
            float vb[4] = {v4.x, v4.y, v4.z, v4.w};
            #pragma unroll
            for (int i = 0; i < 4; ++i)
                #pragma unroll
                for (int j = 0; j < 4; ++j)
                    acc[i][j] += pa[i] * vb[j];
        }
        __syncthreads();   // PV reads done -> next iter may overwrite
    }

    // Normalize and write y[B*T, 1024]
    #pragma unroll
    for (int i = 0; i < 4; ++i) {
        float inv_l = 1.f / l_run[i];
        float4 o;
        o.x = acc[i][0] * inv_l;
        o.y = acc[i][1] * inv_l;
        o.z = acc[i][2] * inv_l;
        o.w = acc[i][3] * inv_l;
        float* dst = y + (long)(b * TT + q0 + (ty << 2) + i) * CC + head_off + (tx << 2);
        *(float4*)dst = o;
    }
}

extern "C" void kernel_launch(void* const* d_in, const int* in_sizes, int n_in,
                              void* d_out, int out_size, void* d_ws, size_t ws_size,
                              hipStream_t stream) {
    const float* x      = (const float*)d_in[0];  // [B,T,C]
    const float* w_attn = (const float*)d_in[1];  // [C, 3C]
    const float* b_attn = (const float*)d_in[2];  // [3C]
    const float* w_proj = (const float*)d_in[3];  // [C, C]
    const float* b_proj = (const float*)d_in[4];  // [C]
    float* out = (float*)d_out;                   // [B,T,C]

    float* qkv = (float*)d_ws;                    // [8192, 3072]  96 MB
    float* yws = qkv + (size_t)NTOK * F3;         // [8192, 1024]  32 MB

    // 1) QKV = x @ w_attn + b_attn
    {
        dim3 grid(F3 / 64, NTOK / 64);
        gemm_bias_kernel<<<grid, 256, 0, stream>>>(x, w_attn, b_attn, qkv,
                                                   NTOK, F3, CC);
    }
    // 2) attention -> y
    {
        dim3 grid(TT / 64, BB * HH);
        attn_kernel<<<grid, 256, 0, stream>>>(qkv, yws);
    }
    // 3) out = y @ w_proj + b_proj
    {
        dim3 grid(CC / 64, NTOK / 64);
        gemm_bias_kernel<<<grid, 256, 0, stream>>>(yws, w_proj, b_proj, out,
                                                   NTOK, CC, CC);
    }
}

// Round 3
// 2019.126 us; speedup vs baseline: 1.9821x; 1.0592x over previous
//
#include <hip/hip_runtime.h>
#include <math.h>

// Problem constants
#define BB 4
#define TT 2048
#define CC 1024
#define HH 16
#define DD 64
#define F3 3072   // 3*C
#define NTOK (BB*TT)  // 8192

// ---------------------------------------------------------------------------
// fp32 GEMM: C[M,N] = A[M,K] @ W[K,N] + bias[N]
// 64x64 tile, BK=16, 256 threads, 4x4 microtile per thread.
// ---------------------------------------------------------------------------
__global__ __launch_bounds__(256, 4) void gemm_bias_kernel(
    const float* __restrict__ A, const float* __restrict__ W,
    const float* __restrict__ bias, float* __restrict__ Cmat,
    int M, int N, int K)
{
    __shared__ float As[16][68];  // [k][m]
    __shared__ float Ws[16][68];  // [k][n]

    const int tid = threadIdx.x;
    const int n0 = blockIdx.x * 64;
    const int m0 = blockIdx.y * 64;
    const int tx = tid & 15;
    const int ty = tid >> 4;

    const int arow = tid >> 2;
    const int acol = (tid & 3) << 2;
    const int wrow = tid >> 4;
    const int wcol = (tid & 15) << 2;

    const float* Aptr = A + (long)(m0 + arow) * K + acol;
    const float* Wptr = W + (long)wrow * N + n0 + wcol;

    float acc[4][4] = {};

    for (int k0 = 0; k0 < K; k0 += 16) {
        float4 av = *(const float4*)(Aptr + k0);
        float4 wv = *(const float4*)(Wptr + (long)k0 * N);
        As[acol + 0][arow] = av.x;
        As[acol + 1][arow] = av.y;
        As[acol + 2][arow] = av.z;
        As[acol + 3][arow] = av.w;
        *(float4*)(&Ws[wrow][wcol]) = wv;
        __syncthreads();
        #pragma unroll
        for (int kk = 0; kk < 16; ++kk) {
            float4 a4 = *(const float4*)(&As[kk][ty << 2]);
            float4 b4 = *(const float4*)(&Ws[kk][tx << 2]);
            float a[4] = {a4.x, a4.y, a4.z, a4.w};
            float b[4] = {b4.x, b4.y, b4.z, b4.w};
            #pragma unroll
            for (int i = 0; i < 4; ++i)
                #pragma unroll
                for (int j = 0; j < 4; ++j)
                    acc[i][j] += a[i] * b[j];
        }
        __syncthreads();
    }

    #pragma unroll
    for (int i = 0; i < 4; ++i) {
        float4 o;
        float* op = &o.x;
        #pragma unroll
        for (int j = 0; j < 4; ++j)
            op[j] = acc[i][j] + bias[n0 + (tx << 2) + j];
        *(float4*)(Cmat + (long)(m0 + (ty << 2) + i) * N + n0 + (tx << 2)) = o;
    }
}

// ---------------------------------------------------------------------------
// Flash attention (fp32), register-resident online softmax.
// Grid: (T/64, B*H), 256 threads, 4x4 microtile per thread.
// __launch_bounds__(256, 3): LDS (52 KB) caps us at 3 blocks/CU = 3 waves/EU
// anyway, so ask the allocator for exactly that -> VGPR budget 170, no
// spills. (R2's implicit cap gave 68 VGPRs -> ~440 MB/dispatch of scratch
// spill traffic to HBM, WRITE_SIZE counter.)
// ---------------------------------------------------------------------------
__global__ __launch_bounds__(256, 3) void attn_kernel(
    const float* __restrict__ qkv, float* __restrict__ y)
{
    __shared__ float QsT[64][68];
    __shared__ float KVs[64][68];
    __shared__ float PsT[64][68];

    const int tid = threadIdx.x;
    const int q0 = blockIdx.x * 64;
    const int bh = blockIdx.y;
    const int b = bh >> 4;
    const int h = bh & 15;
    const int tx = tid & 15;
    const int ty = tid >> 4;
    const long head_off = (long)h * 64;
    const long rowbase = (long)(b * TT) * F3;

    // Stage Q transposed, fold in 1/sqrt(D) = 0.125
    #pragma unroll
    for (int i = 0; i < 4; ++i) {
        int lin = tid + i * 256;
        int r = lin >> 4;
        int d = (lin & 15) << 2;
        const float4 v = *(const float4*)(qkv + rowbase + (long)(q0 + r) * F3 + head_off + d);
        QsT[d + 0][r] = v.x * 0.125f;
        QsT[d + 1][r] = v.y * 0.125f;
        QsT[d + 2][r] = v.z * 0.125f;
        QsT[d + 3][r] = v.w * 0.125f;
    }

    float acc[4][4] = {};
    float m_run[4], l_run[4];
    #pragma unroll
    for (int i = 0; i < 4; ++i) { m_run[i] = -1e30f; l_run[i] = 0.f; }
    __syncthreads();

    for (int k0 = 0; k0 < TT; k0 += 64) {
        // K tile -> registers
        float4 kreg[4];
        int kr[4], kd[4];
        #pragma unroll
        for (int i = 0; i < 4; ++i) {
            int lin = tid + i * 256;
            kr[i] = lin >> 4;
            kd[i] = (lin & 15) << 2;
            kreg[i] = *(const float4*)(qkv + rowbase + (long)(k0 + kr[i]) * F3 + 1024 + head_off + kd[i]);
        }
        // K transposed scatter into KVs[d][k]
        #pragma unroll
        for (int i = 0; i < 4; ++i) {
            KVs[kd[i] + 0][kr[i]] = kreg[i].x;
            KVs[kd[i] + 1][kr[i]] = kreg[i].y;
            KVs[kd[i] + 2][kr[i]] = kreg[i].z;
            KVs[kd[i] + 3][kr[i]] = kreg[i].w;
        }
        __syncthreads();   // K visible

        // Issue V loads early (consumed after next barrier)
        float4 vreg[4];
        int vr[4], vd[4];
        #pragma unroll
        for (int i = 0; i < 4; ++i) {
            int lin = tid + i * 256;
            vr[i] = lin >> 4;
            vd[i] = (lin & 15) << 2;
            vreg[i] = *(const float4*)(qkv + rowbase + (long)(k0 + vr[i]) * F3 + 2048 + head_off + vd[i]);
        }

        // S = Q K^T (outer-product over d)
        float s[4][4] = {};
        #pragma unroll 16
        for (int d = 0; d < 64; ++d) {
            float4 q4 = *(const float4*)(&QsT[d][ty << 2]);
            float4 k4 = *(const float4*)(&KVs[d][tx << 2]);
            float qa[4] = {q4.x, q4.y, q4.z, q4.w};
            float kb[4] = {k4.x, k4.y, k4.z, k4.w};
            #pragma unroll
            for (int i = 0; i < 4; ++i)
                #pragma unroll
                for (int j = 0; j < 4; ++j)
                    s[i][j] += qa[i] * kb[j];
        }

        // Register online softmax
        float mt[4], alpha[4], rsum[4];
        #pragma unroll
        for (int i = 0; i < 4; ++i)
            mt[i] = fmaxf(fmaxf(s[i][0], s[i][1]), fmaxf(s[i][2], s[i][3]));
        #pragma unroll
        for (int off = 1; off < 16; off <<= 1) {
            #pragma unroll
            for (int i = 0; i < 4; ++i)
                mt[i] = fmaxf(mt[i], __shfl_xor(mt[i], off));
        }
        #pragma unroll
        for (int i = 0; i < 4; ++i) {
            float mn = fmaxf(m_run[i], mt[i]);
            alpha[i] = __expf(m_run[i] - mn);
            m_run[i] = mn;
        }
        #pragma unroll
        for (int i = 0; i < 4; ++i) {
            float t = 0.f;
            #pragma unroll
            for (int j = 0; j < 4; ++j) {
                s[i][j] = __expf(s[i][j] - m_run[i]);
                t += s[i][j];
            }
            rsum[i] = t;
        }
        #pragma unroll
        for (int off = 1; off < 16; off <<= 1) {
            #pragma unroll
            for (int i = 0; i < 4; ++i)
                rsum[i] += __shfl_xor(rsum[i], off);
        }
        #pragma unroll
        for (int i = 0; i < 4; ++i) {
            l_run[i] = l_run[i] * alpha[i] + rsum[i];
            #pragma unroll
            for (int j = 0; j < 4; ++j) acc[i][j] *= alpha[i];
        }

        __syncthreads();   // all K reads done -> KVs reusable for V

        // V row-major into KVs[k][d]; P transposed into PsT[k][q]
        #pragma unroll
        for (int i = 0; i < 4; ++i)
            *(float4*)(&KVs[vr[i]][vd[i]]) = vreg[i];
        #pragma unroll
        for (int j = 0; j < 4; ++j) {
            float4 pv = {s[0][j], s[1][j], s[2][j], s[3][j]};
            *(float4*)(&PsT[(tx << 2) + j][ty << 2]) = pv;
        }
        __syncthreads();   // V, P visible

        // O += P V (outer-product over k)
        #pragma unroll 16
        for (int k = 0; k < 64; ++k) {
            float4 p4 = *(const float4*)(&PsT[k][ty << 2]);
            float4 v4 = *(const float4*)(&KVs[k][tx << 2]);
            float pa[4] = {p4.x, p4.y, p4.z, p4.w};
            float vb[4] = {v4.x, v4.y, v4.z, v4.w};
            #pragma unroll
            for (int i = 0; i < 4; ++i)
                #pragma unroll
                for (int j = 0; j < 4; ++j)
                    acc[i][j] += pa[i] * vb[j];
        }
        __syncthreads();   // PV reads done -> next iter may overwrite
    }

    // Normalize and write y[B*T, 1024]
    #pragma unroll
    for (int i = 0; i < 4; ++i) {
        float inv_l = 1.f / l_run[i];
        float4 o;
        o.x = acc[i][0] * inv_l;
        o.y = acc[i][1] * inv_l;
        o.z = acc[i][2] * inv_l;
        o.w = acc[i][3] * inv_l;
        float* dst = y + (long)(b * TT + q0 + (ty << 2) + i) * CC + head_off + (tx << 2);
        *(float4*)dst = o;
    }
}

extern "C" void kernel_launch(void* const* d_in, const int* in_sizes, int n_in,
                              void* d_out, int out_size, void* d_ws, size_t ws_size,
                              hipStream_t stream) {
    const float* x      = (const float*)d_in[0];  // [B,T,C]
    const float* w_attn = (const float*)d_in[1];  // [C, 3C]
    const float* b_attn = (const float*)d_in[2];  // [3C]
    const float* w_proj = (const float*)d_in[3];  // [C, C]
    const float* b_proj = (const float*)d_in[4];  // [C]
    float* out = (float*)d_out;                   // [B,T,C]

    float* qkv = (float*)d_ws;                    // [8192, 3072]  96 MB
    float* yws = qkv + (size_t)NTOK * F3;         // [8192, 1024]  32 MB

    // 1) QKV = x @ w_attn + b_attn
    {
        dim3 grid(F3 / 64, NTOK / 64);
        gemm_bias_kernel<<<grid, 256, 0, stream>>>(x, w_attn, b_attn, qkv,
                                                   NTOK, F3, CC);
    }
    // 2) attention -> y
    {
        dim3 grid(TT / 64, BB * HH);
        attn_kernel<<<grid, 256, 0, stream>>>(qkv, yws);
    }
    // 3) out = y @ w_proj + b_proj
    {
        dim3 grid(CC / 64, NTOK / 64);
        gemm_bias_kernel<<<grid, 256, 0, stream>>>(yws, w_proj, b_proj, out,
                                                   NTOK, CC, CC);
    }
}